// Round 8
// baseline (2279.413 us; speedup 1.0000x reference)
//
#include <hip/hip_runtime.h>
#include <math.h>

#define B_ 8192

typedef __attribute__((ext_vector_type(8))) short short8;
typedef __attribute__((ext_vector_type(4))) float f32x4;

// ---------------- persistent device buffers (rewritten every call) ----------------
// weights (hi/lo split bf16, stored as B^T row-major [N][K])
__device__ float          g_w1t[51200];                    // conv1 [l*25+q][64] fp32, /max_vec
__device__ unsigned short g_w2hi[36864],  g_w2lo[36864];   // conv2 [64][576], k'=(kx*3+ky)*64+ic
__device__ unsigned short g_fc1hi[32768], g_fc1lo[32768];  // fc1   [128][256] (k'=pos*64+oc)
__device__ unsigned short g_enchi[16384], g_enclo[16384];  // enc   [128][128]
__device__ unsigned short g_crhi[131072], g_crlo[131072];  // critic[1024][128]
__device__ unsigned short g_achi[65536],  g_aclo[65536];   // actor [512][128]
__device__ unsigned short g_qWhi[8192],   g_qWlo[8192];    // actor_W^T [16][512]
// activations (hi/lo split bf16)
__device__ unsigned short g_ACT1hi[8192*1024], g_ACT1lo[8192*1024]; // conv1 out [s][cell16*64+oc]
__device__ unsigned short g_A1hi[8192*256],  g_A1lo[8192*256];  // conv2 out [s][pos*64+oc]
__device__ unsigned short g_A2hi[8192*128],  g_A2lo[8192*128];  // fc1 out
__device__ unsigned short g_Hhi[8192*128],   g_Hlo[8192*128];   // enc out (hidden)
__device__ unsigned short g_AFhi[8192*512],  g_AFlo[8192*512];  // actor out

__device__ __forceinline__ unsigned short f2bf(float v){
    unsigned u = __builtin_bit_cast(unsigned, v);
    unsigned r = (u + 0x7fffu + ((u >> 16) & 1u)) >> 16;   // RN-even (finite inputs)
    return (unsigned short)r;
}
__device__ __forceinline__ float bf2f(unsigned short h){
    unsigned u = ((unsigned)h) << 16;
    return __builtin_bit_cast(float, u);
}
__device__ __forceinline__ void split_store(float v, unsigned short* hi, unsigned short* lo){
    unsigned short h = f2bf(v);
    *hi = h;
    *lo = f2bf(v - bf2f(h));
}

// ---------------- prep: transpose + split all weights ----------------
__global__ __launch_bounds__(256) void prep_kernel(
    const float* __restrict__ w1, const float* __restrict__ maxv,
    const float* __restrict__ w2, const float* __restrict__ fc1,
    const float* __restrict__ enc, const float* __restrict__ cr,
    const float* __restrict__ ac, const float* __restrict__ aW)
{
    int d = blockIdx.x * 256 + threadIdx.x;
    if (d < 51200){
        int oc = d & 63, r = d >> 6;
        int l = r / 25, q = r - l*25;
        g_w1t[d] = w1[oc*800 + l*25 + q] / maxv[l];
        return;
    }
    d -= 51200;
    if (d < 36864){
        int oc = d / 576, k2 = d - oc*576;
        int kxy = k2 >> 6, ic = k2 & 63;               // k' = kxy*64 + ic
        split_store(w2[oc*576 + ic*9 + kxy], &g_w2hi[d], &g_w2lo[d]);
        return;
    }
    d -= 36864;
    if (d < 32768){
        int o = d >> 8, kp = d & 255;                  // k' = pos*64+oc
        split_store(fc1[o*256 + (kp & 63)*4 + (kp >> 6)], &g_fc1hi[d], &g_fc1lo[d]);
        return;
    }
    d -= 32768;
    if (d < 16384){ split_store(enc[d], &g_enchi[d], &g_enclo[d]); return; }
    d -= 16384;
    if (d < 131072){ split_store(cr[d], &g_crhi[d], &g_crlo[d]); return; }
    d -= 131072;
    if (d < 65536){ split_store(ac[d], &g_achi[d], &g_aclo[d]); return; }
    d -= 65536;
    { int e = d >> 9, j = d & 511; split_store(aW[j*16 + e], &g_qWhi[d], &g_qWlo[d]); }
}

// ---------------- front-end: batched-ILP branch-free sparse conv1 ----------------
// Each wave owns 50 tokens; processes 5 tokens x 4 directions = 20 unconditional
// weight loads per iteration (all in flight together), then 20 LDS adds into a
// per-wave accumulator (no cross-wave contention). Junk row 16 absorbs invalids.
__global__ __launch_bounds__(256, 4) void frontend_kernel(const int* __restrict__ obs,
                                                          const float* __restrict__ b1)
{
    const int b = blockIdx.x, tid = threadIdx.x;
    __shared__ int   s_obs[600];
    __shared__ int   s_cell[200];
    __shared__ float s_cval[200];
    __shared__ float part4[4][17 * 64];      // per-wave [pos 0..15][oc]; row 16 = junk

    for (int k = tid; k < 600; k += 256) s_obs[k] = obs[b*600 + k];
    {
        float* pp = &part4[0][0];
        for (int k = tid; k < 4*1088; k += 256) pp[k] = 0.f;
    }
    __syncthreads();

    if (tid < 200){
        int coord = s_obs[tid*3], atr = s_obs[tid*3+1], val = s_obs[tid*3+2];
        bool valid = (coord != 255) && (atr < 32);
        int x = (coord >> 4) & 15, y = coord & 15;
        s_cell[tid] = valid ? (atr*256 + x*16 + y) : 0;   // invalid claims cell 0 (ref semantics)
        // x>=14 / y>=14 cells are never read by the 5x5/s3 VALID conv
        s_cval[tid] = (valid && x < 14 && y < 14) ? (float)val : 0.f;
    }
    __syncthreads();
    // last-wins: uniform-trip broadcast loop (all lanes read the same s_cell[j])
    if (tid < 200){
        int c = s_cell[tid];
        bool kept = true;
        #pragma unroll 4
        for (int j = 0; j < 200; j++){
            int cj = s_cell[j];
            kept &= (j <= tid) | (cj != c);
        }
        if (!kept) s_cval[tid] = 0.f;
    }
    __syncthreads();

    // scatter: wave g owns tokens [g*50, g*50+50)
    {
        const int oc = tid & 63, g = tid >> 6;
        float* pg = &part4[g][0];
        const int kbase = g * 50;
        for (int it = 0; it < 10; it++){
            float wv[20], av[20];
            int   tg[20];
            #pragma unroll
            for (int t = 0; t < 5; t++){
                const int k = kbase + it*5 + t;
                const float v = s_cval[k];                // wave-uniform broadcast
                const int c = s_cell[k];
                const int l = c >> 8, x = (c >> 4) & 15, y = c & 15;
                const int x3 = x/3, rx = x - 3*x3;
                const int y3 = y/3, ry = y - 3*y3;
                const float* wl = &g_w1t[l*1600 + oc];
                #pragma unroll
                for (int d = 0; d < 4; d++){
                    const int dx = d >> 1, dy = d & 1;
                    const int ox = x3 - dx, oy = y3 - dy;
                    const int wx = rx + 3*dx, wy = ry + 3*dy;
                    const bool ok = ((unsigned)ox <= 3u) && ((unsigned)oy <= 3u)
                                 && (wx < 5) && (wy < 5);
                    const int woff = ok ? (wx*5 + wy)*64 : 0;   // clamped: always safe
                    wv[t*4+d] = wl[woff];                        // 20 loads batched in flight
                    tg[t*4+d] = (ok ? (ox*4 + oy) : 16)*64 + oc;
                    av[t*4+d] = ok ? v : 0.f;
                }
            }
            #pragma unroll
            for (int s = 0; s < 20; s++)
                atomicAdd(&pg[tg[s]], av[s] * wv[s]);
        }
    }
    __syncthreads();

    // reduce 4 wave-partials + bias + relu, split-store compact act1 [pos][oc]
    for (int r = tid; r < 1024; r += 256){
        int oc2 = r & 63;
        float s = part4[0][r] + part4[1][r] + part4[2][r] + part4[3][r] + b1[oc2];
        float vfin = fmaxf(s, 0.f);
        unsigned short h = f2bf(vfin);
        g_ACT1hi[b*1024 + r] = h;
        g_ACT1lo[b*1024 + r] = f2bf(vfin - bf2f(h));
    }
}

// ---------------- conv2: im2col-on-load MFMA GEMM (M=32768, N=64, K=576) ----------------
__global__ __launch_bounds__(256) void conv2_kernel(const float* __restrict__ bias)
{
    const int r0 = blockIdx.x * 64;                      // 16 samples x 4 pos
    const int tid = threadIdx.x, wave = tid >> 6, lane = tid & 63;
    const int l15 = lane & 15, lhi = lane >> 4;

    __shared__ unsigned short sAhi[64][72];
    __shared__ unsigned short sAlo[64][72];

    f32x4 acc[4] = {{0,0,0,0},{0,0,0,0},{0,0,0,0},{0,0,0,0}};
    for (int kc = 0; kc < 9; kc++){                      // (kx,ky) chunk of 64 k's
        const int kx = kc / 3, ky = kc - 3*kx;
        __syncthreads();
        #pragma unroll
        for (int u = 0; u < 2; u++){
            int unit = tid + u*256;
            int row = unit >> 3, ch8 = (unit & 7) * 8;
            int px = (row >> 1) & 1, py = row & 1;       // pos = row&3
            int cell = (px + kx)*4 + (py + ky);
            int g = ((r0 >> 2) + (row >> 2))*1024 + cell*64 + ch8;
            *(short8*)&sAhi[row][ch8] = *(const short8*)&g_ACT1hi[g];
            *(short8*)&sAlo[row][ch8] = *(const short8*)&g_ACT1lo[g];
        }
        __syncthreads();
        #pragma unroll
        for (int ks = 0; ks < 2; ks++){
            const int kk = ks*32 + lhi*8;
            short8 ah = *(const short8*)&sAhi[wave*16 + l15][kk];
            short8 al = *(const short8*)&sAlo[wave*16 + l15][kk];
            #pragma unroll
            for (int nt = 0; nt < 4; nt++){
                const int n = nt*16 + l15;
                const short8 bh = *(const short8*)&g_w2hi[n*576 + kc*64 + kk];
                const short8 bl = *(const short8*)&g_w2lo[n*576 + kc*64 + kk];
                acc[nt] = __builtin_amdgcn_mfma_f32_16x16x32_bf16(ah, bh, acc[nt], 0, 0, 0);
                acc[nt] = __builtin_amdgcn_mfma_f32_16x16x32_bf16(al, bh, acc[nt], 0, 0, 0);
                acc[nt] = __builtin_amdgcn_mfma_f32_16x16x32_bf16(ah, bl, acc[nt], 0, 0, 0);
            }
        }
    }
    #pragma unroll
    for (int nt = 0; nt < 4; nt++){
        const int col = nt*16 + l15;
        const float bb = bias[col];
        #pragma unroll
        for (int j = 0; j < 4; j++){
            const int row = r0 + wave*16 + lhi*4 + j;
            float v = fmaxf(acc[nt][j] + bb, 0.f);
            unsigned short h = f2bf(v);
            g_A1hi[row*64 + col] = h;                    // == [s][pos*64+oc]
            g_A1lo[row*64 + col] = f2bf(v - bf2f(h));
        }
    }
}

// ---------------- generic 64x64 split-bf16 MFMA GEMM with relu+bias ----------
// LAYER: 1=fc1(K256,N128) 2=enc(K128,N128) 3=actor(K128,N512)
template<int LAYER>
__global__ __launch_bounds__(256) void gemm64_kernel(const float* __restrict__ bias)
{
    constexpr int K = (LAYER==1) ? 256 : 128;
    constexpr int N = (LAYER==3) ? 512 : 128;
    const unsigned short *Ahi, *Alo, *Bh, *Bl;
    unsigned short *Chi, *Clo;
    if constexpr (LAYER==1){ Ahi=g_A1hi; Alo=g_A1lo; Bh=g_fc1hi; Bl=g_fc1lo; Chi=g_A2hi; Clo=g_A2lo; }
    else if constexpr (LAYER==2){ Ahi=g_A2hi; Alo=g_A2lo; Bh=g_enchi; Bl=g_enclo; Chi=g_Hhi;  Clo=g_Hlo; }
    else                        { Ahi=g_Hhi;  Alo=g_Hlo;  Bh=g_achi;  Bl=g_aclo;  Chi=g_AFhi; Clo=g_AFlo; }

    const int r0 = blockIdx.x * 64, c0 = blockIdx.y * 64;
    const int tid = threadIdx.x, wave = tid >> 6, lane = tid & 63;
    const int l15 = lane & 15, lhi = lane >> 4;

    __shared__ unsigned short sAhi[64][72];
    __shared__ unsigned short sAlo[64][72];

    f32x4 acc[4] = {{0,0,0,0},{0,0,0,0},{0,0,0,0},{0,0,0,0}};
    for (int kb = 0; kb < K; kb += 64){
        __syncthreads();
        #pragma unroll
        for (int u = 0; u < 2; u++){
            int unit = tid + u*256;
            int row = unit >> 3, ch = (unit & 7) * 8;
            int g = (r0 + row)*K + kb + ch;
            *(short8*)&sAhi[row][ch] = *(const short8*)&Ahi[g];
            *(short8*)&sAlo[row][ch] = *(const short8*)&Alo[g];
        }
        __syncthreads();
        #pragma unroll
        for (int ks = 0; ks < 2; ks++){
            const int kk = ks*32 + lhi*8;
            short8 ah = *(const short8*)&sAhi[wave*16 + l15][kk];
            short8 al = *(const short8*)&sAlo[wave*16 + l15][kk];
            #pragma unroll
            for (int nt = 0; nt < 4; nt++){
                const int n = c0 + nt*16 + l15;
                const short8 bh = *(const short8*)&Bh[n*K + kb + kk];
                const short8 bl = *(const short8*)&Bl[n*K + kb + kk];
                acc[nt] = __builtin_amdgcn_mfma_f32_16x16x32_bf16(ah, bh, acc[nt], 0, 0, 0);
                acc[nt] = __builtin_amdgcn_mfma_f32_16x16x32_bf16(al, bh, acc[nt], 0, 0, 0);
                acc[nt] = __builtin_amdgcn_mfma_f32_16x16x32_bf16(ah, bl, acc[nt], 0, 0, 0);
            }
        }
    }
    #pragma unroll
    for (int nt = 0; nt < 4; nt++){
        const int col = c0 + nt*16 + l15;
        const float bb = bias[col];
        #pragma unroll
        for (int j = 0; j < 4; j++){
            const int row = r0 + wave*16 + lhi*4 + j;
            float v = fmaxf(acc[nt][j] + bb, 0.f);
            unsigned short h = f2bf(v);
            Chi[row*N + col] = h;
            Clo[row*N + col] = f2bf(v - bf2f(h));
        }
    }
}

// ---------------- critic: [16 rows] x 1024 cols, tanh + vw dot -> value ----------------
__global__ __launch_bounds__(256) void critic_kernel(const float* __restrict__ crb,
    const float* __restrict__ vw, const float* __restrict__ vb, float* __restrict__ outv)
{
    const int r0 = blockIdx.x * 16;
    const int tid = threadIdx.x, wave = tid >> 6, lane = tid & 63;
    const int l15 = lane & 15, lhi = lane >> 4;
    __shared__ unsigned short sAhi[16][136], sAlo[16][136];
    __shared__ float s_v[4][16];
    {
        int row = tid >> 4, ch = (tid & 15) * 8;
        int g = (r0 + row)*128 + ch;
        *(short8*)&sAhi[row][ch] = *(const short8*)&g_Hhi[g];
        *(short8*)&sAlo[row][ch] = *(const short8*)&g_Hlo[g];
    }
    __syncthreads();
    f32x4 acc[16];
    #pragma unroll
    for (int nt = 0; nt < 16; nt++) acc[nt] = f32x4{0,0,0,0};
    #pragma unroll
    for (int ks = 0; ks < 4; ks++){
        const int kk = ks*32 + lhi*8;
        short8 ah = *(const short8*)&sAhi[l15][kk];
        short8 al = *(const short8*)&sAlo[l15][kk];
        #pragma unroll
        for (int nt = 0; nt < 16; nt++){
            const int n = wave*256 + nt*16 + l15;
            const short8 bh = *(const short8*)&g_crhi[n*128 + kk];
            const short8 bl = *(const short8*)&g_crlo[n*128 + kk];
            acc[nt] = __builtin_amdgcn_mfma_f32_16x16x32_bf16(ah, bh, acc[nt], 0, 0, 0);
            acc[nt] = __builtin_amdgcn_mfma_f32_16x16x32_bf16(al, bh, acc[nt], 0, 0, 0);
            acc[nt] = __builtin_amdgcn_mfma_f32_16x16x32_bf16(ah, bl, acc[nt], 0, 0, 0);
        }
    }
    float vp[4] = {0.f, 0.f, 0.f, 0.f};
    #pragma unroll
    for (int nt = 0; nt < 16; nt++){
        const int col = wave*256 + nt*16 + l15;
        const float w = vw[col], bb = crb[col];
        #pragma unroll
        for (int j = 0; j < 4; j++) vp[j] += tanhf(acc[nt][j] + bb) * w;
    }
    #pragma unroll
    for (int m = 1; m < 16; m <<= 1){
        #pragma unroll
        for (int j = 0; j < 4; j++) vp[j] += __shfl_xor(vp[j], m, 64);
    }
    if (l15 == 0){
        #pragma unroll
        for (int j = 0; j < 4; j++) s_v[wave][lhi*4 + j] = vp[j];
    }
    __syncthreads();
    if (tid < 16)
        outv[r0 + tid] = s_v[0][tid] + s_v[1][tid] + s_v[2][tid] + s_v[3][tid] + vb[0];
}

// ---------------- query (AF @ actor_W^T, tanh) fused with logits ----------------
__global__ __launch_bounds__(256) void query_kernel(const float* __restrict__ emb,
    const float* __restrict__ abias, float* __restrict__ out)
{
    const int r0 = blockIdx.x * 64;
    const int tid = threadIdx.x, wave = tid >> 6, lane = tid & 63;
    const int l15 = lane & 15, lhi = lane >> 4;
    __shared__ unsigned short sAhi[64][72], sAlo[64][72];
    __shared__ float s_q[64][16];
    __shared__ float s_emb[1600];
    for (int k = tid; k < 1600; k += 256) s_emb[k] = emb[k];
    f32x4 acc = {0,0,0,0};
    for (int kb = 0; kb < 512; kb += 64){
        __syncthreads();
        #pragma unroll
        for (int u = 0; u < 2; u++){
            int unit = tid + u*256;
            int row = unit >> 3, ch = (unit & 7) * 8;
            int g = (r0 + row)*512 + kb + ch;
            *(short8*)&sAhi[row][ch] = *(const short8*)&g_AFhi[g];
            *(short8*)&sAlo[row][ch] = *(const short8*)&g_AFlo[g];
        }
        __syncthreads();
        #pragma unroll
        for (int ks = 0; ks < 2; ks++){
            const int kk = ks*32 + lhi*8;
            short8 ah = *(const short8*)&sAhi[wave*16 + l15][kk];
            short8 al = *(const short8*)&sAlo[wave*16 + l15][kk];
            const short8 bh = *(const short8*)&g_qWhi[l15*512 + kb + kk];
            const short8 bl = *(const short8*)&g_qWlo[l15*512 + kb + kk];
            acc = __builtin_amdgcn_mfma_f32_16x16x32_bf16(ah, bh, acc, 0, 0, 0);
            acc = __builtin_amdgcn_mfma_f32_16x16x32_bf16(al, bh, acc, 0, 0, 0);
            acc = __builtin_amdgcn_mfma_f32_16x16x32_bf16(ah, bl, acc, 0, 0, 0);
        }
    }
    #pragma unroll
    for (int j = 0; j < 4; j++)
        s_q[wave*16 + lhi*4 + j][l15] = tanhf(acc[j]);
    __syncthreads();
    for (int i = tid; i < 6400; i += 256){
        int row = i / 100, a = i - row*100;
        float s = abias[0];
        #pragma unroll
        for (int e = 0; e < 16; e++) s += s_q[row][e] * s_emb[a*16 + e];
        out[(r0 + row)*100 + a] = s;
    }
}

// ---------------- launch ----------------
extern "C" void kernel_launch(void* const* d_in, const int* in_sizes, int n_in,
                              void* d_out, int out_size, void* d_ws, size_t ws_size,
                              hipStream_t stream) {
    const int*   obs   = (const int*)  d_in[0];
    const float* maxv  = (const float*)d_in[1];
    const float* w1    = (const float*)d_in[2];
    const float* b1    = (const float*)d_in[3];
    const float* w2    = (const float*)d_in[4];
    const float* b2    = (const float*)d_in[5];
    const float* fc1w  = (const float*)d_in[6];
    const float* fc1b  = (const float*)d_in[7];
    const float* encw  = (const float*)d_in[8];
    const float* encb  = (const float*)d_in[9];
    const float* crw   = (const float*)d_in[10];
    const float* crb   = (const float*)d_in[11];
    const float* vw    = (const float*)d_in[12];
    const float* vb    = (const float*)d_in[13];
    const float* acw   = (const float*)d_in[14];
    const float* acb   = (const float*)d_in[15];
    const float* emb   = (const float*)d_in[16];
    const float* aW    = (const float*)d_in[17];
    const float* abias = (const float*)d_in[18];
    float* out = (float*)d_out;

    prep_kernel<<<1336, 256, 0, stream>>>(w1, maxv, w2, fc1w, encw, crw, acw, aW);
    frontend_kernel<<<B_, 256, 0, stream>>>(obs, b1);
    conv2_kernel<<<512, 256, 0, stream>>>(b2);
    gemm64_kernel<1><<<dim3(128, 2), 256, 0, stream>>>(fc1b);  // fc1
    gemm64_kernel<2><<<dim3(128, 2), 256, 0, stream>>>(encb);  // enc
    gemm64_kernel<3><<<dim3(128, 8), 256, 0, stream>>>(acb);   // actor
    critic_kernel<<<512, 256, 0, stream>>>(crb, vw, vb, out + B_*100);
    query_kernel<<<128, 256, 0, stream>>>(emb, abias, out);
}

// Round 9
// 292.607 us; speedup vs baseline: 7.7900x; 7.7900x over previous
//
#include <hip/hip_runtime.h>
#include <math.h>

#define B_ 8192

typedef __attribute__((ext_vector_type(8))) short short8;
typedef __attribute__((ext_vector_type(4))) float f32x4;

// ---------------- persistent device buffers (rewritten every call) ----------------
// weights (hi/lo split bf16, stored as B^T row-major [N][K])
__device__ unsigned short g_w1bh[51200], g_w1bl[51200];    // conv1 W^T [64 oc][800 k=(l,dx,dy)], /maxv
__device__ unsigned short g_w2hi[36864],  g_w2lo[36864];   // conv2 [64][576], k'=(kx*3+ky)*64+ic
__device__ unsigned short g_fc1hi[32768], g_fc1lo[32768];  // fc1   [128][256] (k'=pos*64+oc)
__device__ unsigned short g_enchi[16384], g_enclo[16384];  // enc   [128][128]
__device__ unsigned short g_crhi[131072], g_crlo[131072];  // critic[1024][128]
__device__ unsigned short g_achi[65536],  g_aclo[65536];   // actor [512][128]
__device__ unsigned short g_qWhi[8192],   g_qWlo[8192];    // actor_W^T [16][512]
// activations (hi/lo split bf16)
__device__ unsigned short g_ACT1hi[8192*1024], g_ACT1lo[8192*1024]; // conv1 out [s][pos*64+oc]
__device__ unsigned short g_A1hi[8192*256],  g_A1lo[8192*256];  // conv2 out [s][pos*64+oc]
__device__ unsigned short g_A2hi[8192*128],  g_A2lo[8192*128];  // fc1 out
__device__ unsigned short g_Hhi[8192*128],   g_Hlo[8192*128];   // enc out (hidden)
__device__ unsigned short g_AFhi[8192*512],  g_AFlo[8192*512];  // actor out

__device__ __forceinline__ unsigned short f2bf(float v){
    unsigned u = __builtin_bit_cast(unsigned, v);
    unsigned r = (u + 0x7fffu + ((u >> 16) & 1u)) >> 16;   // RN-even (finite inputs)
    return (unsigned short)r;
}
__device__ __forceinline__ float bf2f(unsigned short h){
    unsigned u = ((unsigned)h) << 16;
    return __builtin_bit_cast(float, u);
}
__device__ __forceinline__ void split_store(float v, unsigned short* hi, unsigned short* lo){
    unsigned short h = f2bf(v);
    *hi = h;
    *lo = f2bf(v - bf2f(h));
}

// ---------------- prep: transpose + split all weights ----------------
__global__ __launch_bounds__(256) void prep_kernel(
    const float* __restrict__ w1, const float* __restrict__ maxv,
    const float* __restrict__ w2, const float* __restrict__ fc1,
    const float* __restrict__ enc, const float* __restrict__ cr,
    const float* __restrict__ ac, const float* __restrict__ aW)
{
    int d = blockIdx.x * 256 + threadIdx.x;
    if (d < 51200){
        // w1 natural layout [oc][l][dx][dy] IS the B^T [oc][k] layout; scale by 1/maxv[l]
        int k = d % 800, l = k / 25;
        split_store(w1[d] / maxv[l], &g_w1bh[d], &g_w1bl[d]);
        return;
    }
    d -= 51200;
    if (d < 36864){
        int oc = d / 576, k2 = d - oc*576;
        int kxy = k2 >> 6, ic = k2 & 63;               // k' = kxy*64 + ic
        split_store(w2[oc*576 + ic*9 + kxy], &g_w2hi[d], &g_w2lo[d]);
        return;
    }
    d -= 36864;
    if (d < 32768){
        int o = d >> 8, kp = d & 255;                  // k' = pos*64+oc
        split_store(fc1[o*256 + (kp & 63)*4 + (kp >> 6)], &g_fc1hi[d], &g_fc1lo[d]);
        return;
    }
    d -= 32768;
    if (d < 16384){ split_store(enc[d], &g_enchi[d], &g_enclo[d]); return; }
    d -= 16384;
    if (d < 131072){ split_store(cr[d], &g_crhi[d], &g_crlo[d]); return; }
    d -= 131072;
    if (d < 65536){ split_store(ac[d], &g_achi[d], &g_aclo[d]); return; }
    d -= 65536;
    { int e = d >> 9, j = d & 511; split_store(aW[j*16 + e], &g_qWhi[d], &g_qWlo[d]); }
}

// ---------------- conv1: scatter -> bf16 im2col A-tile in LDS -> MFMA GEMM ----------------
// 2 samples/block, 512 threads (8 waves). A = [32 rows = si*16+pos][K=800=(l,dx,dy)] bf16
// (box values are integers <=255 -> EXACT in bf16, no lo part needed). B = w1^T hi/lo from L2.
#define APITCH 808   // 800 + 8 shorts pad (keeps 16B alignment, spreads banks)
__global__ __launch_bounds__(512) void conv1_kernel(const int* __restrict__ obs,
                                                    const float* __restrict__ b1)
{
    const int b = blockIdx.x;                 // samples b*2, b*2+1
    const int tid = threadIdx.x;
    const int wave = tid >> 6, lane = tid & 63;
    const int l15 = lane & 15, lhi = lane >> 4;

    __shared__ unsigned short sA[32 * APITCH];      // 51.7 KB
    __shared__ int s_cell[2][200];

    // zero A-tile (vectorized)
    for (int i = tid; i < 4 * APITCH; i += 512)
        *(short8*)&sA[i * 8] = short8{0,0,0,0,0,0,0,0};

    // load my token
    int my_cell = 0, my_l = 0, my_x = 0, my_y = 0;
    float my_val = 0.f;
    bool my_valid = false;
    if (tid < 400){
        const int si = (tid >= 200) ? 1 : 0;
        const int k  = tid - si*200;
        const int base = (b*2 + si)*600 + k*3;
        int coord = obs[base], atr = obs[base+1], val = obs[base+2];
        my_valid = (coord != 255) && (atr < 32);
        my_x = (coord >> 4) & 15;  my_y = coord & 15;  my_l = atr;
        my_cell = my_valid ? (atr*256 + my_x*16 + my_y) : 0;   // invalid claims cell 0 (ref)
        my_val  = my_valid ? (float)val : 0.f;
        s_cell[si][k] = my_cell;
    }
    __syncthreads();
    // last-wins dedup + scatter (writes are exclusive: (pos,l,dx,dy) <-> box cell bijective)
    if (tid < 400){
        const int si = (tid >= 200) ? 1 : 0;
        const int k  = tid - si*200;
        bool kept = true;
        #pragma unroll 4
        for (int j = 0; j < 200; j++){
            int cj = s_cell[si][j];
            kept &= (j <= k) | (cj != my_cell);
        }
        if (kept && my_valid){
            const int x3 = my_x/3, rx = my_x - 3*x3;
            const int y3 = my_y/3, ry = my_y - 3*y3;
            const unsigned short hv = f2bf(my_val);      // exact (integer <= 255)
            #pragma unroll
            for (int d = 0; d < 4; d++){
                const int dxd = d >> 1, dyd = d & 1;
                const int ox = x3 - dxd, oy = y3 - dyd;
                const int wx = rx + 3*dxd, wy = ry + 3*dyd;
                if (((unsigned)ox <= 3u) && ((unsigned)oy <= 3u) && (wx < 5) && (wy < 5))
                    sA[(si*16 + ox*4 + oy)*APITCH + my_l*25 + wx*5 + wy] = hv;
            }
        }
    }
    __syncthreads();

    // MFMA: M=32 (2 tiles) x N=64 (4 tiles) x K=800; wave -> (mt,nt)
    const int mt = wave >> 2, nt = wave & 3;
    const int n = nt*16 + l15;
    const unsigned short* Arow = &sA[(mt*16 + l15)*APITCH];
    const unsigned short* Bh = &g_w1bh[n*800];
    const unsigned short* Bl = &g_w1bl[n*800];
    f32x4 acc = {0,0,0,0};
    #pragma unroll 5
    for (int kb = 0; kb < 800; kb += 32){
        const int kk = kb + lhi*8;
        short8 a  = *(const short8*)&Arow[kk];
        short8 bh = *(const short8*)&Bh[kk];
        short8 bl = *(const short8*)&Bl[kk];
        acc = __builtin_amdgcn_mfma_f32_16x16x32_bf16(a, bh, acc, 0, 0, 0);
        acc = __builtin_amdgcn_mfma_f32_16x16x32_bf16(a, bl, acc, 0, 0, 0);
    }
    const float bb = b1[n];
    #pragma unroll
    for (int j = 0; j < 4; j++){
        const int row = mt*16 + lhi*4 + j;               // = si*16 + pos
        const int si = row >> 4, pos = row & 15;
        float v = fmaxf(acc[j] + bb, 0.f);
        unsigned short h = f2bf(v);
        const int gidx = (b*2 + si)*1024 + pos*64 + n;
        g_ACT1hi[gidx] = h;
        g_ACT1lo[gidx] = f2bf(v - bf2f(h));
    }
}

// ---------------- conv2: im2col-on-load MFMA GEMM (M=32768, N=64, K=576) ----------------
__global__ __launch_bounds__(256) void conv2_kernel(const float* __restrict__ bias)
{
    const int r0 = blockIdx.x * 64;                      // 16 samples x 4 pos
    const int tid = threadIdx.x, wave = tid >> 6, lane = tid & 63;
    const int l15 = lane & 15, lhi = lane >> 4;

    __shared__ unsigned short sAhi[64][72];
    __shared__ unsigned short sAlo[64][72];

    f32x4 acc[4] = {{0,0,0,0},{0,0,0,0},{0,0,0,0},{0,0,0,0}};
    for (int kc = 0; kc < 9; kc++){                      // (kx,ky) chunk of 64 k's
        const int kx = kc / 3, ky = kc - 3*kx;
        __syncthreads();
        #pragma unroll
        for (int u = 0; u < 2; u++){
            int unit = tid + u*256;
            int row = unit >> 3, ch8 = (unit & 7) * 8;
            int px = (row >> 1) & 1, py = row & 1;       // pos = row&3
            int cell = (px + kx)*4 + (py + ky);
            int g = ((r0 >> 2) + (row >> 2))*1024 + cell*64 + ch8;
            *(short8*)&sAhi[row][ch8] = *(const short8*)&g_ACT1hi[g];
            *(short8*)&sAlo[row][ch8] = *(const short8*)&g_ACT1lo[g];
        }
        __syncthreads();
        #pragma unroll
        for (int ks = 0; ks < 2; ks++){
            const int kk = ks*32 + lhi*8;
            short8 ah = *(const short8*)&sAhi[wave*16 + l15][kk];
            short8 al = *(const short8*)&sAlo[wave*16 + l15][kk];
            #pragma unroll
            for (int nt = 0; nt < 4; nt++){
                const int n = nt*16 + l15;
                const short8 bh = *(const short8*)&g_w2hi[n*576 + kc*64 + kk];
                const short8 bl = *(const short8*)&g_w2lo[n*576 + kc*64 + kk];
                acc[nt] = __builtin_amdgcn_mfma_f32_16x16x32_bf16(ah, bh, acc[nt], 0, 0, 0);
                acc[nt] = __builtin_amdgcn_mfma_f32_16x16x32_bf16(al, bh, acc[nt], 0, 0, 0);
                acc[nt] = __builtin_amdgcn_mfma_f32_16x16x32_bf16(ah, bl, acc[nt], 0, 0, 0);
            }
        }
    }
    #pragma unroll
    for (int nt = 0; nt < 4; nt++){
        const int col = nt*16 + l15;
        const float bb = bias[col];
        #pragma unroll
        for (int j = 0; j < 4; j++){
            const int row = r0 + wave*16 + lhi*4 + j;
            float v = fmaxf(acc[nt][j] + bb, 0.f);
            unsigned short h = f2bf(v);
            g_A1hi[row*64 + col] = h;                    // == [s][pos*64+oc]
            g_A1lo[row*64 + col] = f2bf(v - bf2f(h));
        }
    }
}

// ---------------- generic 64x64 split-bf16 MFMA GEMM with relu+bias ----------
// LAYER: 1=fc1(K256,N128) 2=enc(K128,N128) 3=actor(K128,N512)
template<int LAYER>
__global__ __launch_bounds__(256) void gemm64_kernel(const float* __restrict__ bias)
{
    constexpr int K = (LAYER==1) ? 256 : 128;
    constexpr int N = (LAYER==3) ? 512 : 128;
    const unsigned short *Ahi, *Alo, *Bh, *Bl;
    unsigned short *Chi, *Clo;
    if constexpr (LAYER==1){ Ahi=g_A1hi; Alo=g_A1lo; Bh=g_fc1hi; Bl=g_fc1lo; Chi=g_A2hi; Clo=g_A2lo; }
    else if constexpr (LAYER==2){ Ahi=g_A2hi; Alo=g_A2lo; Bh=g_enchi; Bl=g_enclo; Chi=g_Hhi;  Clo=g_Hlo; }
    else                        { Ahi=g_Hhi;  Alo=g_Hlo;  Bh=g_achi;  Bl=g_aclo;  Chi=g_AFhi; Clo=g_AFlo; }

    const int r0 = blockIdx.x * 64, c0 = blockIdx.y * 64;
    const int tid = threadIdx.x, wave = tid >> 6, lane = tid & 63;
    const int l15 = lane & 15, lhi = lane >> 4;

    __shared__ unsigned short sAhi[64][72];
    __shared__ unsigned short sAlo[64][72];

    f32x4 acc[4] = {{0,0,0,0},{0,0,0,0},{0,0,0,0},{0,0,0,0}};
    for (int kb = 0; kb < K; kb += 64){
        __syncthreads();
        #pragma unroll
        for (int u = 0; u < 2; u++){
            int unit = tid + u*256;
            int row = unit >> 3, ch = (unit & 7) * 8;
            int g = (r0 + row)*K + kb + ch;
            *(short8*)&sAhi[row][ch] = *(const short8*)&Ahi[g];
            *(short8*)&sAlo[row][ch] = *(const short8*)&Alo[g];
        }
        __syncthreads();
        #pragma unroll
        for (int ks = 0; ks < 2; ks++){
            const int kk = ks*32 + lhi*8;
            short8 ah = *(const short8*)&sAhi[wave*16 + l15][kk];
            short8 al = *(const short8*)&sAlo[wave*16 + l15][kk];
            #pragma unroll
            for (int nt = 0; nt < 4; nt++){
                const int n = c0 + nt*16 + l15;
                const short8 bh = *(const short8*)&Bh[n*K + kb + kk];
                const short8 bl = *(const short8*)&Bl[n*K + kb + kk];
                acc[nt] = __builtin_amdgcn_mfma_f32_16x16x32_bf16(ah, bh, acc[nt], 0, 0, 0);
                acc[nt] = __builtin_amdgcn_mfma_f32_16x16x32_bf16(al, bh, acc[nt], 0, 0, 0);
                acc[nt] = __builtin_amdgcn_mfma_f32_16x16x32_bf16(ah, bl, acc[nt], 0, 0, 0);
            }
        }
    }
    #pragma unroll
    for (int nt = 0; nt < 4; nt++){
        const int col = c0 + nt*16 + l15;
        const float bb = bias[col];
        #pragma unroll
        for (int j = 0; j < 4; j++){
            const int row = r0 + wave*16 + lhi*4 + j;
            float v = fmaxf(acc[nt][j] + bb, 0.f);
            unsigned short h = f2bf(v);
            Chi[row*N + col] = h;
            Clo[row*N + col] = f2bf(v - bf2f(h));
        }
    }
}

// ---------------- critic: [16 rows] x 1024 cols, tanh + vw dot -> value ----------------
__global__ __launch_bounds__(256) void critic_kernel(const float* __restrict__ crb,
    const float* __restrict__ vw, const float* __restrict__ vb, float* __restrict__ outv)
{
    const int r0 = blockIdx.x * 16;
    const int tid = threadIdx.x, wave = tid >> 6, lane = tid & 63;
    const int l15 = lane & 15, lhi = lane >> 4;
    __shared__ unsigned short sAhi[16][136], sAlo[16][136];
    __shared__ float s_v[4][16];
    {
        int row = tid >> 4, ch = (tid & 15) * 8;
        int g = (r0 + row)*128 + ch;
        *(short8*)&sAhi[row][ch] = *(const short8*)&g_Hhi[g];
        *(short8*)&sAlo[row][ch] = *(const short8*)&g_Hlo[g];
    }
    __syncthreads();
    f32x4 acc[16];
    #pragma unroll
    for (int nt = 0; nt < 16; nt++) acc[nt] = f32x4{0,0,0,0};
    #pragma unroll
    for (int ks = 0; ks < 4; ks++){
        const int kk = ks*32 + lhi*8;
        short8 ah = *(const short8*)&sAhi[l15][kk];
        short8 al = *(const short8*)&sAlo[l15][kk];
        #pragma unroll
        for (int nt = 0; nt < 16; nt++){
            const int n = wave*256 + nt*16 + l15;
            const short8 bh = *(const short8*)&g_crhi[n*128 + kk];
            const short8 bl = *(const short8*)&g_crlo[n*128 + kk];
            acc[nt] = __builtin_amdgcn_mfma_f32_16x16x32_bf16(ah, bh, acc[nt], 0, 0, 0);
            acc[nt] = __builtin_amdgcn_mfma_f32_16x16x32_bf16(al, bh, acc[nt], 0, 0, 0);
            acc[nt] = __builtin_amdgcn_mfma_f32_16x16x32_bf16(ah, bl, acc[nt], 0, 0, 0);
        }
    }
    float vp[4] = {0.f, 0.f, 0.f, 0.f};
    #pragma unroll
    for (int nt = 0; nt < 16; nt++){
        const int col = wave*256 + nt*16 + l15;
        const float w = vw[col], bb = crb[col];
        #pragma unroll
        for (int j = 0; j < 4; j++) vp[j] += tanhf(acc[nt][j] + bb) * w;
    }
    #pragma unroll
    for (int m = 1; m < 16; m <<= 1){
        #pragma unroll
        for (int j = 0; j < 4; j++) vp[j] += __shfl_xor(vp[j], m, 64);
    }
    if (l15 == 0){
        #pragma unroll
        for (int j = 0; j < 4; j++) s_v[wave][lhi*4 + j] = vp[j];
    }
    __syncthreads();
    if (tid < 16)
        outv[r0 + tid] = s_v[0][tid] + s_v[1][tid] + s_v[2][tid] + s_v[3][tid] + vb[0];
}

// ---------------- query (AF @ actor_W^T, tanh) fused with logits ----------------
__global__ __launch_bounds__(256) void query_kernel(const float* __restrict__ emb,
    const float* __restrict__ abias, float* __restrict__ out)
{
    const int r0 = blockIdx.x * 64;
    const int tid = threadIdx.x, wave = tid >> 6, lane = tid & 63;
    const int l15 = lane & 15, lhi = lane >> 4;
    __shared__ unsigned short sAhi[64][72], sAlo[64][72];
    __shared__ float s_q[64][16];
    __shared__ float s_emb[1600];
    for (int k = tid; k < 1600; k += 256) s_emb[k] = emb[k];
    f32x4 acc = {0,0,0,0};
    for (int kb = 0; kb < 512; kb += 64){
        __syncthreads();
        #pragma unroll
        for (int u = 0; u < 2; u++){
            int unit = tid + u*256;
            int row = unit >> 3, ch = (unit & 7) * 8;
            int g = (r0 + row)*512 + kb + ch;
            *(short8*)&sAhi[row][ch] = *(const short8*)&g_AFhi[g];
            *(short8*)&sAlo[row][ch] = *(const short8*)&g_AFlo[g];
        }
        __syncthreads();
        #pragma unroll
        for (int ks = 0; ks < 2; ks++){
            const int kk = ks*32 + lhi*8;
            short8 ah = *(const short8*)&sAhi[wave*16 + l15][kk];
            short8 al = *(const short8*)&sAlo[wave*16 + l15][kk];
            const short8 bh = *(const short8*)&g_qWhi[l15*512 + kb + kk];
            const short8 bl = *(const short8*)&g_qWlo[l15*512 + kb + kk];
            acc = __builtin_amdgcn_mfma_f32_16x16x32_bf16(ah, bh, acc, 0, 0, 0);
            acc = __builtin_amdgcn_mfma_f32_16x16x32_bf16(al, bh, acc, 0, 0, 0);
            acc = __builtin_amdgcn_mfma_f32_16x16x32_bf16(ah, bl, acc, 0, 0, 0);
        }
    }
    #pragma unroll
    for (int j = 0; j < 4; j++)
        s_q[wave*16 + lhi*4 + j][l15] = tanhf(acc[j]);
    __syncthreads();
    for (int i = tid; i < 6400; i += 256){
        int row = i / 100, a = i - row*100;
        float s = abias[0];
        #pragma unroll
        for (int e = 0; e < 16; e++) s += s_q[row][e] * s_emb[a*16 + e];
        out[(r0 + row)*100 + a] = s;
    }
}

// ---------------- launch ----------------
extern "C" void kernel_launch(void* const* d_in, const int* in_sizes, int n_in,
                              void* d_out, int out_size, void* d_ws, size_t ws_size,
                              hipStream_t stream) {
    const int*   obs   = (const int*)  d_in[0];
    const float* maxv  = (const float*)d_in[1];
    const float* w1    = (const float*)d_in[2];
    const float* b1    = (const float*)d_in[3];
    const float* w2    = (const float*)d_in[4];
    const float* b2    = (const float*)d_in[5];
    const float* fc1w  = (const float*)d_in[6];
    const float* fc1b  = (const float*)d_in[7];
    const float* encw  = (const float*)d_in[8];
    const float* encb  = (const float*)d_in[9];
    const float* crw   = (const float*)d_in[10];
    const float* crb   = (const float*)d_in[11];
    const float* vw    = (const float*)d_in[12];
    const float* vb    = (const float*)d_in[13];
    const float* acw   = (const float*)d_in[14];
    const float* acb   = (const float*)d_in[15];
    const float* emb   = (const float*)d_in[16];
    const float* aW    = (const float*)d_in[17];
    const float* abias = (const float*)d_in[18];
    float* out = (float*)d_out;

    prep_kernel<<<1336, 256, 0, stream>>>(w1, maxv, w2, fc1w, encw, crw, acw, aW);
    conv1_kernel<<<B_/2, 512, 0, stream>>>(obs, b1);
    conv2_kernel<<<512, 256, 0, stream>>>(b2);
    gemm64_kernel<1><<<dim3(128, 2), 256, 0, stream>>>(fc1b);  // fc1
    gemm64_kernel<2><<<dim3(128, 2), 256, 0, stream>>>(encb);  // enc
    gemm64_kernel<3><<<dim3(128, 8), 256, 0, stream>>>(acb);   // actor
    critic_kernel<<<512, 256, 0, stream>>>(crb, vw, vb, out + B_*100);
    query_kernel<<<128, 256, 0, stream>>>(emb, abias, out);
}

// Round 10
// 250.701 us; speedup vs baseline: 9.0922x; 1.1672x over previous
//
#include <hip/hip_runtime.h>
#include <math.h>

#define B_ 8192

typedef __attribute__((ext_vector_type(8))) short short8;
typedef __attribute__((ext_vector_type(4))) float f32x4;

// ---------------- persistent device buffers (rewritten every call) ----------------
// weights (hi/lo split bf16, stored as B^T row-major [N][K])
__device__ unsigned short g_w1bh[51200], g_w1bl[51200];    // conv1 W^T [64 oc][800 k=(l,dx,dy)], /maxv
__device__ unsigned short g_w2hi[36864],  g_w2lo[36864];   // conv2 [64][576], k'=(kx*3+ky)*64+ic
__device__ unsigned short g_fc1hi[32768], g_fc1lo[32768];  // fc1   [128][256] (k'=pos*64+oc)
__device__ unsigned short g_enchi[16384], g_enclo[16384];  // enc   [128][128]
__device__ unsigned short g_crhi[131072], g_crlo[131072];  // critic[1024][128]
__device__ unsigned short g_achi[65536],  g_aclo[65536];   // actor [512][128]
__device__ unsigned short g_qWhi[8192],   g_qWlo[8192];    // actor_W^T [16][512]
// activations (hi/lo split bf16)
__device__ unsigned short g_ACT1hi[8192*1024], g_ACT1lo[8192*1024]; // conv1 out [s][pos*64+oc]
__device__ unsigned short g_A1hi[8192*256],  g_A1lo[8192*256];  // conv2 out [s][pos*64+oc]
__device__ unsigned short g_A2hi[8192*128],  g_A2lo[8192*128];  // fc1 out
__device__ unsigned short g_Hhi[8192*128],   g_Hlo[8192*128];   // enc out (hidden)
__device__ unsigned short g_AFhi[8192*512],  g_AFlo[8192*512];  // actor out

__device__ __forceinline__ unsigned short f2bf(float v){
    unsigned u = __builtin_bit_cast(unsigned, v);
    unsigned r = (u + 0x7fffu + ((u >> 16) & 1u)) >> 16;   // RN-even (finite inputs)
    return (unsigned short)r;
}
__device__ __forceinline__ float bf2f(unsigned short h){
    unsigned u = ((unsigned)h) << 16;
    return __builtin_bit_cast(float, u);
}
__device__ __forceinline__ void split_store(float v, unsigned short* hi, unsigned short* lo){
    unsigned short h = f2bf(v);
    *hi = h;
    *lo = f2bf(v - bf2f(h));
}

// ---------------- prep: transpose + split all weights ----------------
__global__ __launch_bounds__(256) void prep_kernel(
    const float* __restrict__ w1, const float* __restrict__ maxv,
    const float* __restrict__ w2, const float* __restrict__ fc1,
    const float* __restrict__ enc, const float* __restrict__ cr,
    const float* __restrict__ ac, const float* __restrict__ aW)
{
    int d = blockIdx.x * 256 + threadIdx.x;
    if (d < 51200){
        // w1 natural layout [oc][l][dx][dy] IS the B^T [oc][k] layout; scale by 1/maxv[l]
        int k = d % 800, l = k / 25;
        split_store(w1[d] / maxv[l], &g_w1bh[d], &g_w1bl[d]);
        return;
    }
    d -= 51200;
    if (d < 36864){
        int oc = d / 576, k2 = d - oc*576;
        int kxy = k2 >> 6, ic = k2 & 63;               // k' = kxy*64 + ic
        split_store(w2[oc*576 + ic*9 + kxy], &g_w2hi[d], &g_w2lo[d]);
        return;
    }
    d -= 36864;
    if (d < 32768){
        int o = d >> 8, kp = d & 255;                  // k' = pos*64+oc
        split_store(fc1[o*256 + (kp & 63)*4 + (kp >> 6)], &g_fc1hi[d], &g_fc1lo[d]);
        return;
    }
    d -= 32768;
    if (d < 16384){ split_store(enc[d], &g_enchi[d], &g_enclo[d]); return; }
    d -= 16384;
    if (d < 131072){ split_store(cr[d], &g_crhi[d], &g_crlo[d]); return; }
    d -= 131072;
    if (d < 65536){ split_store(ac[d], &g_achi[d], &g_aclo[d]); return; }
    d -= 65536;
    { int e = d >> 9, j = d & 511; split_store(aW[j*16 + e], &g_qWhi[d], &g_qWlo[d]); }
}

// ---------------- conv1: scatter -> bf16 im2col A-tile in LDS -> MFMA GEMM ----------------
// 2 samples/block, 256 threads (4 waves). A = [32 rows = si*16+pos][K=800] bf16 (exact).
// Wave = nt (unique 16 B-rows); each wave computes BOTH m-tiles per B-load (2x B reuse),
// with explicit next-chunk B prefetch so L2 latency hides under 4 MFMAs.
#define APITCH 808   // 800 + 8 shorts pad (16B-aligned rows, bank-quad stride 5 mod 8)
__global__ __launch_bounds__(256) void conv1_kernel(const int* __restrict__ obs,
                                                    const float* __restrict__ b1)
{
    const int b = blockIdx.x;                 // samples b*2, b*2+1
    const int tid = threadIdx.x;
    const int wave = tid >> 6, lane = tid & 63;
    const int l15 = lane & 15, lhi = lane >> 4;

    __shared__ unsigned short sA[32 * APITCH];      // 51.7 KB
    __shared__ int s_cell[2][200];

    // zero A-tile (vectorized)
    for (int i = tid; i < 4 * APITCH; i += 256)
        *(short8*)&sA[i * 8] = short8{0,0,0,0,0,0,0,0};

    // load token slots (tid and tid+256)
    int   cells[2], xs[2], ys[2], ls[2];
    float vals[2];
    bool  valids[2];
    #pragma unroll
    for (int u = 0; u < 2; u++){
        const int slot = tid + u*256;
        valids[u] = false; cells[u] = 0;
        if (slot < 400){
            const int si = (slot >= 200) ? 1 : 0;
            const int k  = slot - si*200;
            const int base = (b*2 + si)*600 + k*3;
            int coord = obs[base], atr = obs[base+1], val = obs[base+2];
            bool valid = (coord != 255) && (atr < 32);
            xs[u] = (coord >> 4) & 15;  ys[u] = coord & 15;  ls[u] = atr;
            cells[u] = valid ? (atr*256 + xs[u]*16 + ys[u]) : 0;   // invalid claims cell 0
            vals[u]  = (float)val;
            valids[u] = valid;
            s_cell[si][k] = cells[u];
        }
    }
    __syncthreads();
    // last-wins dedup + scatter (writes exclusive: (pos,l,dx,dy) <-> box cell bijective;
    // x>=14 / y>=14 taps are auto-excluded by the wx/wy < 5 bounds)
    #pragma unroll
    for (int u = 0; u < 2; u++){
        const int slot = tid + u*256;
        if (slot < 400){
            const int si = (slot >= 200) ? 1 : 0;
            const int k  = slot - si*200;
            const int c  = cells[u];
            bool kept = true;
            #pragma unroll 4
            for (int j = 0; j < 200; j++){
                int cj = s_cell[si][j];
                kept &= (j <= k) | (cj != c);
            }
            if (kept && valids[u]){
                const int x3 = xs[u]/3, rx = xs[u] - 3*x3;
                const int y3 = ys[u]/3, ry = ys[u] - 3*y3;
                const unsigned short hv = f2bf(vals[u]);     // exact (integer <= 255)
                #pragma unroll
                for (int d = 0; d < 4; d++){
                    const int dxd = d >> 1, dyd = d & 1;
                    const int ox = x3 - dxd, oy = y3 - dyd;
                    const int wx = rx + 3*dxd, wy = ry + 3*dyd;
                    if (((unsigned)ox <= 3u) && ((unsigned)oy <= 3u) && (wx < 5) && (wy < 5))
                        sA[(si*16 + ox*4 + oy)*APITCH + ls[u]*25 + wx*5 + wy] = hv;
                }
            }
        }
    }
    __syncthreads();

    // MFMA: wave = nt; n = wave*16 + l15; both m-tiles per B-load; prefetched B.
    const int n = wave*16 + l15;
    const unsigned short* Bh = &g_w1bh[n*800];
    const unsigned short* Bl = &g_w1bl[n*800];
    const unsigned short* A0 = &sA[l15*APITCH];
    const unsigned short* A1 = &sA[(16 + l15)*APITCH];
    f32x4 acc0 = {0,0,0,0}, acc1 = {0,0,0,0};
    short8 bh = *(const short8*)&Bh[lhi*8];
    short8 bl = *(const short8*)&Bl[lhi*8];
    #pragma unroll
    for (int kc = 0; kc < 25; kc++){
        const int kk = kc*32 + lhi*8;
        short8 a0 = *(const short8*)&A0[kk];
        short8 a1 = *(const short8*)&A1[kk];
        short8 bhn, bln;
        if (kc < 24){
            bhn = *(const short8*)&Bh[kk + 32];
            bln = *(const short8*)&Bl[kk + 32];
        }
        acc0 = __builtin_amdgcn_mfma_f32_16x16x32_bf16(a0, bh, acc0, 0, 0, 0);
        acc1 = __builtin_amdgcn_mfma_f32_16x16x32_bf16(a1, bh, acc1, 0, 0, 0);
        acc0 = __builtin_amdgcn_mfma_f32_16x16x32_bf16(a0, bl, acc0, 0, 0, 0);
        acc1 = __builtin_amdgcn_mfma_f32_16x16x32_bf16(a1, bl, acc1, 0, 0, 0);
        bh = bhn; bl = bln;
    }
    const float bb = b1[n];
    #pragma unroll
    for (int j = 0; j < 4; j++){
        const int pos = lhi*4 + j;
        float v0 = fmaxf(acc0[j] + bb, 0.f);
        float v1 = fmaxf(acc1[j] + bb, 0.f);
        unsigned short h0 = f2bf(v0), h1 = f2bf(v1);
        const int g0 = (b*2    )*1024 + pos*64 + n;
        const int g1 = (b*2 + 1)*1024 + pos*64 + n;
        g_ACT1hi[g0] = h0;  g_ACT1lo[g0] = f2bf(v0 - bf2f(h0));
        g_ACT1hi[g1] = h1;  g_ACT1lo[g1] = f2bf(v1 - bf2f(h1));
    }
}

// ---------------- conv2: im2col-on-load MFMA GEMM (M=32768, N=64, K=576) ----------------
__global__ __launch_bounds__(256) void conv2_kernel(const float* __restrict__ bias)
{
    const int r0 = blockIdx.x * 64;                      // 16 samples x 4 pos
    const int tid = threadIdx.x, wave = tid >> 6, lane = tid & 63;
    const int l15 = lane & 15, lhi = lane >> 4;

    __shared__ unsigned short sAhi[64][72];
    __shared__ unsigned short sAlo[64][72];

    f32x4 acc[4] = {{0,0,0,0},{0,0,0,0},{0,0,0,0},{0,0,0,0}};
    for (int kc = 0; kc < 9; kc++){                      // (kx,ky) chunk of 64 k's
        const int kx = kc / 3, ky = kc - 3*kx;
        __syncthreads();
        #pragma unroll
        for (int u = 0; u < 2; u++){
            int unit = tid + u*256;
            int row = unit >> 3, ch8 = (unit & 7) * 8;
            int px = (row >> 1) & 1, py = row & 1;       // pos = row&3
            int cell = (px + kx)*4 + (py + ky);
            int g = ((r0 >> 2) + (row >> 2))*1024 + cell*64 + ch8;
            *(short8*)&sAhi[row][ch8] = *(const short8*)&g_ACT1hi[g];
            *(short8*)&sAlo[row][ch8] = *(const short8*)&g_ACT1lo[g];
        }
        __syncthreads();
        #pragma unroll
        for (int ks = 0; ks < 2; ks++){
            const int kk = ks*32 + lhi*8;
            short8 ah = *(const short8*)&sAhi[wave*16 + l15][kk];
            short8 al = *(const short8*)&sAlo[wave*16 + l15][kk];
            #pragma unroll
            for (int nt = 0; nt < 4; nt++){
                const int n = nt*16 + l15;
                const short8 bh = *(const short8*)&g_w2hi[n*576 + kc*64 + kk];
                const short8 bl = *(const short8*)&g_w2lo[n*576 + kc*64 + kk];
                acc[nt] = __builtin_amdgcn_mfma_f32_16x16x32_bf16(ah, bh, acc[nt], 0, 0, 0);
                acc[nt] = __builtin_amdgcn_mfma_f32_16x16x32_bf16(al, bh, acc[nt], 0, 0, 0);
                acc[nt] = __builtin_amdgcn_mfma_f32_16x16x32_bf16(ah, bl, acc[nt], 0, 0, 0);
            }
        }
    }
    #pragma unroll
    for (int nt = 0; nt < 4; nt++){
        const int col = nt*16 + l15;
        const float bb = bias[col];
        #pragma unroll
        for (int j = 0; j < 4; j++){
            const int row = r0 + wave*16 + lhi*4 + j;
            float v = fmaxf(acc[nt][j] + bb, 0.f);
            unsigned short h = f2bf(v);
            g_A1hi[row*64 + col] = h;                    // == [s][pos*64+oc]
            g_A1lo[row*64 + col] = f2bf(v - bf2f(h));
        }
    }
}

// ---------------- generic 64x64 split-bf16 MFMA GEMM with relu+bias ----------
// LAYER: 1=fc1(K256,N128) 2=enc(K128,N128) 3=actor(K128,N512)
template<int LAYER>
__global__ __launch_bounds__(256) void gemm64_kernel(const float* __restrict__ bias)
{
    constexpr int K = (LAYER==1) ? 256 : 128;
    constexpr int N = (LAYER==3) ? 512 : 128;
    const unsigned short *Ahi, *Alo, *Bh, *Bl;
    unsigned short *Chi, *Clo;
    if constexpr (LAYER==1){ Ahi=g_A1hi; Alo=g_A1lo; Bh=g_fc1hi; Bl=g_fc1lo; Chi=g_A2hi; Clo=g_A2lo; }
    else if constexpr (LAYER==2){ Ahi=g_A2hi; Alo=g_A2lo; Bh=g_enchi; Bl=g_enclo; Chi=g_Hhi;  Clo=g_Hlo; }
    else                        { Ahi=g_Hhi;  Alo=g_Hlo;  Bh=g_achi;  Bl=g_aclo;  Chi=g_AFhi; Clo=g_AFlo; }

    const int r0 = blockIdx.x * 64, c0 = blockIdx.y * 64;
    const int tid = threadIdx.x, wave = tid >> 6, lane = tid & 63;
    const int l15 = lane & 15, lhi = lane >> 4;

    __shared__ unsigned short sAhi[64][72];
    __shared__ unsigned short sAlo[64][72];

    f32x4 acc[4] = {{0,0,0,0},{0,0,0,0},{0,0,0,0},{0,0,0,0}};
    for (int kb = 0; kb < K; kb += 64){
        __syncthreads();
        #pragma unroll
        for (int u = 0; u < 2; u++){
            int unit = tid + u*256;
            int row = unit >> 3, ch = (unit & 7) * 8;
            int g = (r0 + row)*K + kb + ch;
            *(short8*)&sAhi[row][ch] = *(const short8*)&Ahi[g];
            *(short8*)&sAlo[row][ch] = *(const short8*)&Alo[g];
        }
        __syncthreads();
        #pragma unroll
        for (int ks = 0; ks < 2; ks++){
            const int kk = ks*32 + lhi*8;
            short8 ah = *(const short8*)&sAhi[wave*16 + l15][kk];
            short8 al = *(const short8*)&sAlo[wave*16 + l15][kk];
            #pragma unroll
            for (int nt = 0; nt < 4; nt++){
                const int n = c0 + nt*16 + l15;
                const short8 bh = *(const short8*)&Bh[n*K + kb + kk];
                const short8 bl = *(const short8*)&Bl[n*K + kb + kk];
                acc[nt] = __builtin_amdgcn_mfma_f32_16x16x32_bf16(ah, bh, acc[nt], 0, 0, 0);
                acc[nt] = __builtin_amdgcn_mfma_f32_16x16x32_bf16(al, bh, acc[nt], 0, 0, 0);
                acc[nt] = __builtin_amdgcn_mfma_f32_16x16x32_bf16(ah, bl, acc[nt], 0, 0, 0);
            }
        }
    }
    #pragma unroll
    for (int nt = 0; nt < 4; nt++){
        const int col = c0 + nt*16 + l15;
        const float bb = bias[col];
        #pragma unroll
        for (int j = 0; j < 4; j++){
            const int row = r0 + wave*16 + lhi*4 + j;
            float v = fmaxf(acc[nt][j] + bb, 0.f);
            unsigned short h = f2bf(v);
            Chi[row*N + col] = h;
            Clo[row*N + col] = f2bf(v - bf2f(h));
        }
    }
}

// ---------------- critic: [16 rows] x 1024 cols, tanh + vw dot -> value ----------------
__global__ __launch_bounds__(256) void critic_kernel(const float* __restrict__ crb,
    const float* __restrict__ vw, const float* __restrict__ vb, float* __restrict__ outv)
{
    const int r0 = blockIdx.x * 16;
    const int tid = threadIdx.x, wave = tid >> 6, lane = tid & 63;
    const int l15 = lane & 15, lhi = lane >> 4;
    __shared__ unsigned short sAhi[16][136], sAlo[16][136];
    __shared__ float s_v[4][16];
    {
        int row = tid >> 4, ch = (tid & 15) * 8;
        int g = (r0 + row)*128 + ch;
        *(short8*)&sAhi[row][ch] = *(const short8*)&g_Hhi[g];
        *(short8*)&sAlo[row][ch] = *(const short8*)&g_Hlo[g];
    }
    __syncthreads();
    f32x4 acc[16];
    #pragma unroll
    for (int nt = 0; nt < 16; nt++) acc[nt] = f32x4{0,0,0,0};
    #pragma unroll
    for (int ks = 0; ks < 4; ks++){
        const int kk = ks*32 + lhi*8;
        short8 ah = *(const short8*)&sAhi[l15][kk];
        short8 al = *(const short8*)&sAlo[l15][kk];
        #pragma unroll
        for (int nt = 0; nt < 16; nt++){
            const int n = wave*256 + nt*16 + l15;
            const short8 bh = *(const short8*)&g_crhi[n*128 + kk];
            const short8 bl = *(const short8*)&g_crlo[n*128 + kk];
            acc[nt] = __builtin_amdgcn_mfma_f32_16x16x32_bf16(ah, bh, acc[nt], 0, 0, 0);
            acc[nt] = __builtin_amdgcn_mfma_f32_16x16x32_bf16(al, bh, acc[nt], 0, 0, 0);
            acc[nt] = __builtin_amdgcn_mfma_f32_16x16x32_bf16(ah, bl, acc[nt], 0, 0, 0);
        }
    }
    float vp[4] = {0.f, 0.f, 0.f, 0.f};
    #pragma unroll
    for (int nt = 0; nt < 16; nt++){
        const int col = wave*256 + nt*16 + l15;
        const float w = vw[col], bb = crb[col];
        #pragma unroll
        for (int j = 0; j < 4; j++) vp[j] += tanhf(acc[nt][j] + bb) * w;
    }
    #pragma unroll
    for (int m = 1; m < 16; m <<= 1){
        #pragma unroll
        for (int j = 0; j < 4; j++) vp[j] += __shfl_xor(vp[j], m, 64);
    }
    if (l15 == 0){
        #pragma unroll
        for (int j = 0; j < 4; j++) s_v[wave][lhi*4 + j] = vp[j];
    }
    __syncthreads();
    if (tid < 16)
        outv[r0 + tid] = s_v[0][tid] + s_v[1][tid] + s_v[2][tid] + s_v[3][tid] + vb[0];
}

// ---------------- query (AF @ actor_W^T, tanh) fused with logits ----------------
__global__ __launch_bounds__(256) void query_kernel(const float* __restrict__ emb,
    const float* __restrict__ abias, float* __restrict__ out)
{
    const int r0 = blockIdx.x * 64;
    const int tid = threadIdx.x, wave = tid >> 6, lane = tid & 63;
    const int l15 = lane & 15, lhi = lane >> 4;
    __shared__ unsigned short sAhi[64][72], sAlo[64][72];
    __shared__ float s_q[64][16];
    __shared__ float s_emb[1600];
    for (int k = tid; k < 1600; k += 256) s_emb[k] = emb[k];
    f32x4 acc = {0,0,0,0};
    for (int kb = 0; kb < 512; kb += 64){
        __syncthreads();
        #pragma unroll
        for (int u = 0; u < 2; u++){
            int unit = tid + u*256;
            int row = unit >> 3, ch = (unit & 7) * 8;
            int g = (r0 + row)*512 + kb + ch;
            *(short8*)&sAhi[row][ch] = *(const short8*)&g_AFhi[g];
            *(short8*)&sAlo[row][ch] = *(const short8*)&g_AFlo[g];
        }
        __syncthreads();
        #pragma unroll
        for (int ks = 0; ks < 2; ks++){
            const int kk = ks*32 + lhi*8;
            short8 ah = *(const short8*)&sAhi[wave*16 + l15][kk];
            short8 al = *(const short8*)&sAlo[wave*16 + l15][kk];
            const short8 bh = *(const short8*)&g_qWhi[l15*512 + kb + kk];
            const short8 bl = *(const short8*)&g_qWlo[l15*512 + kb + kk];
            acc = __builtin_amdgcn_mfma_f32_16x16x32_bf16(ah, bh, acc, 0, 0, 0);
            acc = __builtin_amdgcn_mfma_f32_16x16x32_bf16(al, bh, acc, 0, 0, 0);
            acc = __builtin_amdgcn_mfma_f32_16x16x32_bf16(ah, bl, acc, 0, 0, 0);
        }
    }
    #pragma unroll
    for (int j = 0; j < 4; j++)
        s_q[wave*16 + lhi*4 + j][l15] = tanhf(acc[j]);
    __syncthreads();
    for (int i = tid; i < 6400; i += 256){
        int row = i / 100, a = i - row*100;
        float s = abias[0];
        #pragma unroll
        for (int e = 0; e < 16; e++) s += s_q[row][e] * s_emb[a*16 + e];
        out[(r0 + row)*100 + a] = s;
    }
}

// ---------------- launch ----------------
extern "C" void kernel_launch(void* const* d_in, const int* in_sizes, int n_in,
                              void* d_out, int out_size, void* d_ws, size_t ws_size,
                              hipStream_t stream) {
    const int*   obs   = (const int*)  d_in[0];
    const float* maxv  = (const float*)d_in[1];
    const float* w1    = (const float*)d_in[2];
    const float* b1    = (const float*)d_in[3];
    const float* w2    = (const float*)d_in[4];
    const float* b2    = (const float*)d_in[5];
    const float* fc1w  = (const float*)d_in[6];
    const float* fc1b  = (const float*)d_in[7];
    const float* encw  = (const float*)d_in[8];
    const float* encb  = (const float*)d_in[9];
    const float* crw   = (const float*)d_in[10];
    const float* crb   = (const float*)d_in[11];
    const float* vw    = (const float*)d_in[12];
    const float* vb    = (const float*)d_in[13];
    const float* acw   = (const float*)d_in[14];
    const float* acb   = (const float*)d_in[15];
    const float* emb   = (const float*)d_in[16];
    const float* aW    = (const float*)d_in[17];
    const float* abias = (const float*)d_in[18];
    float* out = (float*)d_out;

    prep_kernel<<<1336, 256, 0, stream>>>(w1, maxv, w2, fc1w, encw, crw, acw, aW);
    conv1_kernel<<<B_/2, 256, 0, stream>>>(obs, b1);
    conv2_kernel<<<512, 256, 0, stream>>>(b2);
    gemm64_kernel<1><<<dim3(128, 2), 256, 0, stream>>>(fc1b);  // fc1
    gemm64_kernel<2><<<dim3(128, 2), 256, 0, stream>>>(encb);  // enc
    gemm64_kernel<3><<<dim3(128, 8), 256, 0, stream>>>(acb);   // actor
    critic_kernel<<<512, 256, 0, stream>>>(crb, vw, vb, out + B_*100);
    query_kernel<<<128, 256, 0, stream>>>(emb, abias, out);
}

// Round 11
// 235.654 us; speedup vs baseline: 9.6727x; 1.0639x over previous
//
#include <hip/hip_runtime.h>
#include <math.h>

#define B_ 8192

typedef __attribute__((ext_vector_type(8))) short short8;
typedef __attribute__((ext_vector_type(4))) float f32x4;

// ---------------- persistent device buffers (rewritten every call) ----------------
// weights (hi/lo split bf16, stored as B^T row-major [N][K])
__device__ unsigned short g_w1bh[51200], g_w1bl[51200];    // conv1 W^T [64 oc][800 k], /maxv
__device__ unsigned short g_w2hi[36864],  g_w2lo[36864];   // conv2 [64][576], k'=(kx*3+ky)*64+ic
__device__ unsigned short g_fc1hi[32768], g_fc1lo[32768];  // fc1   [128][256] (k'=pos*64+oc)
__device__ unsigned short g_enchi[16384], g_enclo[16384];  // enc   [128][128]
__device__ unsigned short g_crhi[131072], g_crlo[131072];  // critic[1024][128]
__device__ unsigned short g_achi[65536],  g_aclo[65536];   // actor [512][128]
__device__ unsigned short g_qWhi[8192],   g_qWlo[8192];    // actor_W^T [16][512]
// activations (hi/lo split bf16)
__device__ unsigned short g_ACT1hi[8192*1024], g_ACT1lo[8192*1024]; // conv1 out [s][pos*64+oc]
__device__ unsigned short g_A1hi[8192*256],  g_A1lo[8192*256];  // conv2 out [s][pos*64+oc]
__device__ unsigned short g_Hhi[8192*128],   g_Hlo[8192*128];   // enc out (hidden)

__device__ __forceinline__ unsigned short f2bf(float v){
    unsigned u = __builtin_bit_cast(unsigned, v);
    unsigned r = (u + 0x7fffu + ((u >> 16) & 1u)) >> 16;   // RN-even (finite inputs)
    return (unsigned short)r;
}
__device__ __forceinline__ float bf2f(unsigned short h){
    unsigned u = ((unsigned)h) << 16;
    return __builtin_bit_cast(float, u);
}
__device__ __forceinline__ void split_store(float v, unsigned short* hi, unsigned short* lo){
    unsigned short h = f2bf(v);
    *hi = h;
    *lo = f2bf(v - bf2f(h));
}

// ---------------- prep: transpose + split all weights ----------------
__global__ __launch_bounds__(256) void prep_kernel(
    const float* __restrict__ w1, const float* __restrict__ maxv,
    const float* __restrict__ w2, const float* __restrict__ fc1,
    const float* __restrict__ enc, const float* __restrict__ cr,
    const float* __restrict__ ac, const float* __restrict__ aW)
{
    int d = blockIdx.x * 256 + threadIdx.x;
    if (d < 51200){
        int k = d % 800, l = k / 25;
        split_store(w1[d] / maxv[l], &g_w1bh[d], &g_w1bl[d]);
        return;
    }
    d -= 51200;
    if (d < 36864){
        int oc = d / 576, k2 = d - oc*576;
        int kxy = k2 >> 6, ic = k2 & 63;               // k' = kxy*64 + ic
        split_store(w2[oc*576 + ic*9 + kxy], &g_w2hi[d], &g_w2lo[d]);
        return;
    }
    d -= 36864;
    if (d < 32768){
        int o = d >> 8, kp = d & 255;                  // k' = pos*64+oc
        split_store(fc1[o*256 + (kp & 63)*4 + (kp >> 6)], &g_fc1hi[d], &g_fc1lo[d]);
        return;
    }
    d -= 32768;
    if (d < 16384){ split_store(enc[d], &g_enchi[d], &g_enclo[d]); return; }
    d -= 16384;
    if (d < 131072){ split_store(cr[d], &g_crhi[d], &g_crlo[d]); return; }
    d -= 131072;
    if (d < 65536){ split_store(ac[d], &g_achi[d], &g_aclo[d]); return; }
    d -= 65536;
    { int e = d >> 9, j = d & 511; split_store(aW[j*16 + e], &g_qWhi[d], &g_qWlo[d]); }
}

// ---------------- conv1: scatter -> bf16 im2col A-tile in LDS -> MFMA GEMM ----------------
// 2 samples/block, 256 threads (4 waves). Wave = nt; both m-tiles per B-load; 2-deep B prefetch.
#define APITCH 808   // 800 + 8 shorts pad
__global__ __launch_bounds__(256) void conv1_kernel(const int* __restrict__ obs,
                                                    const float* __restrict__ b1)
{
    const int b = blockIdx.x;                 // samples b*2, b*2+1
    const int tid = threadIdx.x;
    const int wave = tid >> 6, lane = tid & 63;
    const int l15 = lane & 15, lhi = lane >> 4;

    __shared__ unsigned short sA[32 * APITCH];      // 51.7 KB
    __shared__ int s_cell[2][200];

    for (int i = tid; i < 4 * APITCH; i += 256)
        *(short8*)&sA[i * 8] = short8{0,0,0,0,0,0,0,0};

    int   cells[2], xs[2], ys[2], ls[2];
    float vals[2];
    bool  valids[2];
    #pragma unroll
    for (int u = 0; u < 2; u++){
        const int slot = tid + u*256;
        valids[u] = false; cells[u] = 0;
        if (slot < 400){
            const int si = (slot >= 200) ? 1 : 0;
            const int k  = slot - si*200;
            const int base = (b*2 + si)*600 + k*3;
            int coord = obs[base], atr = obs[base+1], val = obs[base+2];
            bool valid = (coord != 255) && (atr < 32);
            xs[u] = (coord >> 4) & 15;  ys[u] = coord & 15;  ls[u] = atr;
            cells[u] = valid ? (atr*256 + xs[u]*16 + ys[u]) : 0;   // invalid claims cell 0
            vals[u]  = (float)val;
            valids[u] = valid;
            s_cell[si][k] = cells[u];
        }
    }
    __syncthreads();
    #pragma unroll
    for (int u = 0; u < 2; u++){
        const int slot = tid + u*256;
        if (slot < 400){
            const int si = (slot >= 200) ? 1 : 0;
            const int k  = slot - si*200;
            const int c  = cells[u];
            bool kept = true;
            #pragma unroll 4
            for (int j = 0; j < 200; j++){
                int cj = s_cell[si][j];
                kept &= (j <= k) | (cj != c);
            }
            if (kept && valids[u]){
                const int x3 = xs[u]/3, rx = xs[u] - 3*x3;
                const int y3 = ys[u]/3, ry = ys[u] - 3*y3;
                const unsigned short hv = f2bf(vals[u]);     // exact (integer <= 255)
                #pragma unroll
                for (int d = 0; d < 4; d++){
                    const int dxd = d >> 1, dyd = d & 1;
                    const int ox = x3 - dxd, oy = y3 - dyd;
                    const int wx = rx + 3*dxd, wy = ry + 3*dyd;
                    if (((unsigned)ox <= 3u) && ((unsigned)oy <= 3u) && (wx < 5) && (wy < 5))
                        sA[(si*16 + ox*4 + oy)*APITCH + ls[u]*25 + wx*5 + wy] = hv;
                }
            }
        }
    }
    __syncthreads();

    const int n = wave*16 + l15;
    const unsigned short* Bh = &g_w1bh[n*800];
    const unsigned short* Bl = &g_w1bl[n*800];
    const unsigned short* A0 = &sA[l15*APITCH];
    const unsigned short* A1 = &sA[(16 + l15)*APITCH];
    f32x4 acc0 = {0,0,0,0}, acc1 = {0,0,0,0};
    short8 bh0 = *(const short8*)&Bh[lhi*8];
    short8 bl0 = *(const short8*)&Bl[lhi*8];
    short8 bh1 = *(const short8*)&Bh[32 + lhi*8];
    short8 bl1 = *(const short8*)&Bl[32 + lhi*8];
    #pragma unroll
    for (int kc = 0; kc < 25; kc++){
        const int kk = kc*32 + lhi*8;
        short8 a0 = *(const short8*)&A0[kk];
        short8 a1 = *(const short8*)&A1[kk];
        short8 bhn, bln;
        if (kc < 23){
            bhn = *(const short8*)&Bh[kk + 64];
            bln = *(const short8*)&Bl[kk + 64];
        }
        acc0 = __builtin_amdgcn_mfma_f32_16x16x32_bf16(a0, bh0, acc0, 0, 0, 0);
        acc1 = __builtin_amdgcn_mfma_f32_16x16x32_bf16(a1, bh0, acc1, 0, 0, 0);
        acc0 = __builtin_amdgcn_mfma_f32_16x16x32_bf16(a0, bl0, acc0, 0, 0, 0);
        acc1 = __builtin_amdgcn_mfma_f32_16x16x32_bf16(a1, bl0, acc1, 0, 0, 0);
        bh0 = bh1; bl0 = bl1; bh1 = bhn; bl1 = bln;
    }
    const float bb = b1[n];
    #pragma unroll
    for (int j = 0; j < 4; j++){
        const int pos = lhi*4 + j;
        float v0 = fmaxf(acc0[j] + bb, 0.f);
        float v1 = fmaxf(acc1[j] + bb, 0.f);
        unsigned short h0 = f2bf(v0), h1 = f2bf(v1);
        const int g0 = (b*2    )*1024 + pos*64 + n;
        const int g1 = (b*2 + 1)*1024 + pos*64 + n;
        g_ACT1hi[g0] = h0;  g_ACT1lo[g0] = f2bf(v0 - bf2f(h0));
        g_ACT1hi[g1] = h1;  g_ACT1lo[g1] = f2bf(v1 - bf2f(h1));
    }
}

// ---------------- conv2: im2col-on-load MFMA GEMM (M=32768, N=64, K=576) ----------------
__global__ __launch_bounds__(256) void conv2_kernel(const float* __restrict__ bias)
{
    const int r0 = blockIdx.x * 64;                      // 16 samples x 4 pos
    const int tid = threadIdx.x, wave = tid >> 6, lane = tid & 63;
    const int l15 = lane & 15, lhi = lane >> 4;

    __shared__ unsigned short sAhi[64][72];
    __shared__ unsigned short sAlo[64][72];

    f32x4 acc[4] = {{0,0,0,0},{0,0,0,0},{0,0,0,0},{0,0,0,0}};
    for (int kc = 0; kc < 9; kc++){                      // (kx,ky) chunk of 64 k's
        const int kx = kc / 3, ky = kc - 3*kx;
        __syncthreads();
        #pragma unroll
        for (int u = 0; u < 2; u++){
            int unit = tid + u*256;
            int row = unit >> 3, ch8 = (unit & 7) * 8;
            int px = (row >> 1) & 1, py = row & 1;       // pos = row&3
            int cell = (px + kx)*4 + (py + ky);
            int g = ((r0 >> 2) + (row >> 2))*1024 + cell*64 + ch8;
            *(short8*)&sAhi[row][ch8] = *(const short8*)&g_ACT1hi[g];
            *(short8*)&sAlo[row][ch8] = *(const short8*)&g_ACT1lo[g];
        }
        __syncthreads();
        #pragma unroll
        for (int ks = 0; ks < 2; ks++){
            const int kk = ks*32 + lhi*8;
            short8 ah = *(const short8*)&sAhi[wave*16 + l15][kk];
            short8 al = *(const short8*)&sAlo[wave*16 + l15][kk];
            #pragma unroll
            for (int nt = 0; nt < 4; nt++){
                const int n = nt*16 + l15;
                const short8 bh = *(const short8*)&g_w2hi[n*576 + kc*64 + kk];
                const short8 bl = *(const short8*)&g_w2lo[n*576 + kc*64 + kk];
                acc[nt] = __builtin_amdgcn_mfma_f32_16x16x32_bf16(ah, bh, acc[nt], 0, 0, 0);
                acc[nt] = __builtin_amdgcn_mfma_f32_16x16x32_bf16(al, bh, acc[nt], 0, 0, 0);
                acc[nt] = __builtin_amdgcn_mfma_f32_16x16x32_bf16(ah, bl, acc[nt], 0, 0, 0);
            }
        }
    }
    #pragma unroll
    for (int nt = 0; nt < 4; nt++){
        const int col = nt*16 + l15;
        const float bb = bias[col];
        #pragma unroll
        for (int j = 0; j < 4; j++){
            const int row = r0 + wave*16 + lhi*4 + j;
            float v = fmaxf(acc[nt][j] + bb, 0.f);
            unsigned short h = f2bf(v);
            g_A1hi[row*64 + col] = h;                    // == [s][pos*64+oc]
            g_A1lo[row*64 + col] = f2bf(v - bf2f(h));
        }
    }
}

// ---------------- tailA: fc1 + enc fused (32 samples/block, chained via LDS) ----------------
__global__ __launch_bounds__(256) void tailA_kernel(const float* __restrict__ fc1b,
                                                    const float* __restrict__ encb)
{
    const int r0 = blockIdx.x * 32;
    const int tid = threadIdx.x, wave = tid >> 6, lane = tid & 63;
    const int l15 = lane & 15, lhi = lane >> 4;

    __shared__ unsigned short sA1h[32][264], sA1l[32][264];   // 33.8 KB
    __shared__ unsigned short sXh[32][136],  sXl[32][136];    // 17.4 KB

    // stage A1 [32][256] hi/lo
    for (int u = tid; u < 1024; u += 256){
        int row = u >> 5, ch8 = (u & 31) * 8;
        *(short8*)&sA1h[row][ch8] = *(const short8*)&g_A1hi[(r0+row)*256 + ch8];
        *(short8*)&sA1l[row][ch8] = *(const short8*)&g_A1lo[(r0+row)*256 + ch8];
    }
    __syncthreads();

    // fc1: M=32, N=128 (wave owns nt = 2w, 2w+1), K=256
    {
        f32x4 acc[2][2] = {{{0,0,0,0},{0,0,0,0}},{{0,0,0,0},{0,0,0,0}}}; // [t][mt]
        #pragma unroll
        for (int kk8 = 0; kk8 < 8; kk8++){
            const int kk = kk8*32 + lhi*8;
            short8 ah0 = *(const short8*)&sA1h[l15][kk];
            short8 al0 = *(const short8*)&sA1l[l15][kk];
            short8 ah1 = *(const short8*)&sA1h[16 + l15][kk];
            short8 al1 = *(const short8*)&sA1l[16 + l15][kk];
            #pragma unroll
            for (int t = 0; t < 2; t++){
                const int n = (wave*2 + t)*16 + l15;
                const short8 bh = *(const short8*)&g_fc1hi[n*256 + kk];
                const short8 bl = *(const short8*)&g_fc1lo[n*256 + kk];
                acc[t][0] = __builtin_amdgcn_mfma_f32_16x16x32_bf16(ah0, bh, acc[t][0], 0, 0, 0);
                acc[t][1] = __builtin_amdgcn_mfma_f32_16x16x32_bf16(ah1, bh, acc[t][1], 0, 0, 0);
                acc[t][0] = __builtin_amdgcn_mfma_f32_16x16x32_bf16(al0, bh, acc[t][0], 0, 0, 0);
                acc[t][1] = __builtin_amdgcn_mfma_f32_16x16x32_bf16(al1, bh, acc[t][1], 0, 0, 0);
                acc[t][0] = __builtin_amdgcn_mfma_f32_16x16x32_bf16(ah0, bl, acc[t][0], 0, 0, 0);
                acc[t][1] = __builtin_amdgcn_mfma_f32_16x16x32_bf16(ah1, bl, acc[t][1], 0, 0, 0);
            }
        }
        #pragma unroll
        for (int t = 0; t < 2; t++){
            const int col = (wave*2 + t)*16 + l15;
            const float bb = fc1b[col];
            #pragma unroll
            for (int mt = 0; mt < 2; mt++){
                #pragma unroll
                for (int j = 0; j < 4; j++){
                    const int row = mt*16 + lhi*4 + j;
                    float v = fmaxf(acc[t][mt][j] + bb, 0.f);
                    unsigned short h = f2bf(v);
                    sXh[row][col] = h;
                    sXl[row][col] = f2bf(v - bf2f(h));
                }
            }
        }
    }
    __syncthreads();

    // enc: M=32, N=128, K=128 -> H global (hi/lo)
    {
        f32x4 acc[2][2] = {{{0,0,0,0},{0,0,0,0}},{{0,0,0,0},{0,0,0,0}}};
        #pragma unroll
        for (int kk4 = 0; kk4 < 4; kk4++){
            const int kk = kk4*32 + lhi*8;
            short8 ah0 = *(const short8*)&sXh[l15][kk];
            short8 al0 = *(const short8*)&sXl[l15][kk];
            short8 ah1 = *(const short8*)&sXh[16 + l15][kk];
            short8 al1 = *(const short8*)&sXl[16 + l15][kk];
            #pragma unroll
            for (int t = 0; t < 2; t++){
                const int n = (wave*2 + t)*16 + l15;
                const short8 bh = *(const short8*)&g_enchi[n*128 + kk];
                const short8 bl = *(const short8*)&g_enclo[n*128 + kk];
                acc[t][0] = __builtin_amdgcn_mfma_f32_16x16x32_bf16(ah0, bh, acc[t][0], 0, 0, 0);
                acc[t][1] = __builtin_amdgcn_mfma_f32_16x16x32_bf16(ah1, bh, acc[t][1], 0, 0, 0);
                acc[t][0] = __builtin_amdgcn_mfma_f32_16x16x32_bf16(al0, bh, acc[t][0], 0, 0, 0);
                acc[t][1] = __builtin_amdgcn_mfma_f32_16x16x32_bf16(al1, bh, acc[t][1], 0, 0, 0);
                acc[t][0] = __builtin_amdgcn_mfma_f32_16x16x32_bf16(ah0, bl, acc[t][0], 0, 0, 0);
                acc[t][1] = __builtin_amdgcn_mfma_f32_16x16x32_bf16(ah1, bl, acc[t][1], 0, 0, 0);
            }
        }
        #pragma unroll
        for (int t = 0; t < 2; t++){
            const int col = (wave*2 + t)*16 + l15;
            const float bb = encb[col];
            #pragma unroll
            for (int mt = 0; mt < 2; mt++){
                #pragma unroll
                for (int j = 0; j < 4; j++){
                    const int row = mt*16 + lhi*4 + j;
                    float v = fmaxf(acc[t][mt][j] + bb, 0.f);
                    unsigned short h = f2bf(v);
                    const int gi = (r0 + row)*128 + col;
                    g_Hhi[gi] = h;
                    g_Hlo[gi] = f2bf(v - bf2f(h));
                }
            }
        }
    }
}

// ---------------- tailB: critic + actor + query + logits fused (32 samples/block) ---------
__global__ __launch_bounds__(256, 2) void tailB_kernel(
    const float* __restrict__ crb, const float* __restrict__ vw,
    const float* __restrict__ vb,  const float* __restrict__ acb,
    const float* __restrict__ emb, const float* __restrict__ abias,
    float* __restrict__ out)
{
    const int r0 = blockIdx.x * 32;
    const int tid = threadIdx.x, wave = tid >> 6, lane = tid & 63;
    const int l15 = lane & 15, lhi = lane >> 4;

    __shared__ unsigned short sHh[32][136], sHl[32][136];     // 17.4 KB
    __shared__ unsigned short cbh[4][32][72], cbl[4][32][72]; // 36.9 KB per-wave actor chunks
    __shared__ float qpart[4][32][16];                        // 8 KB
    __shared__ float sq[32][17];                              // 2.2 KB
    __shared__ float svred[4][32];                            // 0.5 KB
    __shared__ float semb[1600];                              // 6.4 KB

    for (int u = tid; u < 512; u += 256){
        int row = u >> 4, ch8 = (u & 15) * 8;
        *(short8*)&sHh[row][ch8] = *(const short8*)&g_Hhi[(r0+row)*128 + ch8];
        *(short8*)&sHl[row][ch8] = *(const short8*)&g_Hlo[(r0+row)*128 + ch8];
    }
    for (int k = tid; k < 1600; k += 256) semb[k] = emb[k];
    __syncthreads();

    // hoist H A-fragments (shared by critic and actor; K=128)
    short8 Ah[2][4], Al[2][4];
    #pragma unroll
    for (int mt = 0; mt < 2; mt++)
        #pragma unroll
        for (int kk4 = 0; kk4 < 4; kk4++){
            const int kk = kk4*32 + lhi*8;
            Ah[mt][kk4] = *(const short8*)&sHh[mt*16 + l15][kk];
            Al[mt][kk4] = *(const short8*)&sHl[mt*16 + l15][kk];
        }

    // ---- critic: wave owns 256 cols; tanh + vw dot ----
    {
        f32x4 cacc[2][16];
        #pragma unroll
        for (int mt = 0; mt < 2; mt++)
            #pragma unroll
            for (int nt = 0; nt < 16; nt++) cacc[mt][nt] = f32x4{0,0,0,0};
        #pragma unroll
        for (int nt = 0; nt < 16; nt++){
            const int n = wave*256 + nt*16 + l15;
            #pragma unroll
            for (int kk4 = 0; kk4 < 4; kk4++){
                const int kk = kk4*32 + lhi*8;
                const short8 bh = *(const short8*)&g_crhi[n*128 + kk];
                const short8 bl = *(const short8*)&g_crlo[n*128 + kk];
                cacc[0][nt] = __builtin_amdgcn_mfma_f32_16x16x32_bf16(Ah[0][kk4], bh, cacc[0][nt], 0, 0, 0);
                cacc[1][nt] = __builtin_amdgcn_mfma_f32_16x16x32_bf16(Ah[1][kk4], bh, cacc[1][nt], 0, 0, 0);
                cacc[0][nt] = __builtin_amdgcn_mfma_f32_16x16x32_bf16(Al[0][kk4], bh, cacc[0][nt], 0, 0, 0);
                cacc[1][nt] = __builtin_amdgcn_mfma_f32_16x16x32_bf16(Al[1][kk4], bh, cacc[1][nt], 0, 0, 0);
                cacc[0][nt] = __builtin_amdgcn_mfma_f32_16x16x32_bf16(Ah[0][kk4], bl, cacc[0][nt], 0, 0, 0);
                cacc[1][nt] = __builtin_amdgcn_mfma_f32_16x16x32_bf16(Ah[1][kk4], bl, cacc[1][nt], 0, 0, 0);
            }
        }
        float vp[8] = {0,0,0,0,0,0,0,0};       // [mt*4+j]
        #pragma unroll
        for (int nt = 0; nt < 16; nt++){
            const int n = wave*256 + nt*16 + l15;
            const float w = vw[n], bb = crb[n];
            #pragma unroll
            for (int mt = 0; mt < 2; mt++)
                #pragma unroll
                for (int j = 0; j < 4; j++)
                    vp[mt*4+j] += tanhf(cacc[mt][nt][j] + bb) * w;
        }
        #pragma unroll
        for (int m = 1; m < 16; m <<= 1)
            #pragma unroll
            for (int q = 0; q < 8; q++) vp[q] += __shfl_xor(vp[q], m, 64);
        if (l15 == 0){
            #pragma unroll
            for (int mt = 0; mt < 2; mt++)
                #pragma unroll
                for (int j = 0; j < 4; j++)
                    svred[wave][mt*16 + lhi*4 + j] = vp[mt*4+j];
        }
    }

    // ---- actor chunks + query mini-GEMM (wave-split K) ----
    f32x4 qacc[2] = {{0,0,0,0},{0,0,0,0}};
    #pragma unroll
    for (int cc = 0; cc < 2; cc++){
        const int c = wave*2 + cc;                       // chunk 0..7 (64 actor cols each)
        f32x4 aacc[2][4];
        #pragma unroll
        for (int mt = 0; mt < 2; mt++)
            #pragma unroll
            for (int nt = 0; nt < 4; nt++) aacc[mt][nt] = f32x4{0,0,0,0};
        #pragma unroll
        for (int kk4 = 0; kk4 < 4; kk4++){
            const int kk = kk4*32 + lhi*8;
            #pragma unroll
            for (int nt = 0; nt < 4; nt++){
                const int n = c*64 + nt*16 + l15;
                const short8 bh = *(const short8*)&g_achi[n*128 + kk];
                const short8 bl = *(const short8*)&g_aclo[n*128 + kk];
                aacc[0][nt] = __builtin_amdgcn_mfma_f32_16x16x32_bf16(Ah[0][kk4], bh, aacc[0][nt], 0, 0, 0);
                aacc[1][nt] = __builtin_amdgcn_mfma_f32_16x16x32_bf16(Ah[1][kk4], bh, aacc[1][nt], 0, 0, 0);
                aacc[0][nt] = __builtin_amdgcn_mfma_f32_16x16x32_bf16(Al[0][kk4], bh, aacc[0][nt], 0, 0, 0);
                aacc[1][nt] = __builtin_amdgcn_mfma_f32_16x16x32_bf16(Al[1][kk4], bh, aacc[1][nt], 0, 0, 0);
                aacc[0][nt] = __builtin_amdgcn_mfma_f32_16x16x32_bf16(Ah[0][kk4], bl, aacc[0][nt], 0, 0, 0);
                aacc[1][nt] = __builtin_amdgcn_mfma_f32_16x16x32_bf16(Ah[1][kk4], bl, aacc[1][nt], 0, 0, 0);
            }
        }
        // relu + bias -> per-wave LDS chunk [32 rows][64 cols]
        #pragma unroll
        for (int nt = 0; nt < 4; nt++){
            const int col = nt*16 + l15;
            const float bb = acb[c*64 + col];
            #pragma unroll
            for (int mt = 0; mt < 2; mt++)
                #pragma unroll
                for (int j = 0; j < 4; j++){
                    const int row = mt*16 + lhi*4 + j;
                    float v = fmaxf(aacc[mt][nt][j] + bb, 0.f);
                    unsigned short h = f2bf(v);
                    cbh[wave][row][col] = h;
                    cbl[wave][row][col] = f2bf(v - bf2f(h));
                }
        }
        // query partial over this chunk (K=64), B = qW^T rows e=l15
        #pragma unroll
        for (int kk2 = 0; kk2 < 2; kk2++){
            const int kk = kk2*32 + lhi*8;
            const short8 qbh = *(const short8*)&g_qWhi[l15*512 + c*64 + kk];
            const short8 qbl = *(const short8*)&g_qWlo[l15*512 + c*64 + kk];
            #pragma unroll
            for (int mt = 0; mt < 2; mt++){
                const short8 qah = *(const short8*)&cbh[wave][mt*16 + l15][kk];
                const short8 qal = *(const short8*)&cbl[wave][mt*16 + l15][kk];
                qacc[mt] = __builtin_amdgcn_mfma_f32_16x16x32_bf16(qah, qbh, qacc[mt], 0, 0, 0);
                qacc[mt] = __builtin_amdgcn_mfma_f32_16x16x32_bf16(qal, qbh, qacc[mt], 0, 0, 0);
                qacc[mt] = __builtin_amdgcn_mfma_f32_16x16x32_bf16(qah, qbl, qacc[mt], 0, 0, 0);
            }
        }
    }
    #pragma unroll
    for (int mt = 0; mt < 2; mt++)
        #pragma unroll
        for (int j = 0; j < 4; j++)
            qpart[wave][mt*16 + lhi*4 + j][l15] = qacc[mt][j];
    __syncthreads();

    // value out
    if (tid < 32)
        out[B_*100 + r0 + tid] = svred[0][tid] + svred[1][tid] + svred[2][tid]
                               + svred[3][tid] + vb[0];
    // finalize q
    for (int i = tid; i < 512; i += 256){
        int row = i >> 4, e = i & 15;
        sq[row][e] = tanhf(qpart[0][row][e] + qpart[1][row][e]
                         + qpart[2][row][e] + qpart[3][row][e]);
    }
    __syncthreads();
    // logits
    for (int i = tid; i < 3200; i += 256){
        int row = i / 100, a = i - row*100;
        float s = abias[0];
        #pragma unroll
        for (int e = 0; e < 16; e++) s += sq[row][e] * semb[a*16 + e];
        out[(r0 + row)*100 + a] = s;
    }
}

// ---------------- launch ----------------
extern "C" void kernel_launch(void* const* d_in, const int* in_sizes, int n_in,
                              void* d_out, int out_size, void* d_ws, size_t ws_size,
                              hipStream_t stream) {
    const int*   obs   = (const int*)  d_in[0];
    const float* maxv  = (const float*)d_in[1];
    const float* w1    = (const float*)d_in[2];
    const float* b1    = (const float*)d_in[3];
    const float* w2    = (const float*)d_in[4];
    const float* b2    = (const float*)d_in[5];
    const float* fc1w  = (const float*)d_in[6];
    const float* fc1b  = (const float*)d_in[7];
    const float* encw  = (const float*)d_in[8];
    const float* encb  = (const float*)d_in[9];
    const float* crw   = (const float*)d_in[10];
    const float* crb   = (const float*)d_in[11];
    const float* vw    = (const float*)d_in[12];
    const float* vb    = (const float*)d_in[13];
    const float* acw   = (const float*)d_in[14];
    const float* acb   = (const float*)d_in[15];
    const float* emb   = (const float*)d_in[16];
    const float* aW    = (const float*)d_in[17];
    const float* abias = (const float*)d_in[18];
    float* out = (float*)d_out;

    prep_kernel<<<1336, 256, 0, stream>>>(w1, maxv, w2, fc1w, encw, crw, acw, aW);
    conv1_kernel<<<B_/2, 256, 0, stream>>>(obs, b1);
    conv2_kernel<<<512, 256, 0, stream>>>(b2);
    tailA_kernel<<<256, 256, 0, stream>>>(fc1b, encb);
    tailB_kernel<<<256, 256, 0, stream>>>(crb, vw, vb, acb, emb, abias, out);
}